// Round 1
// baseline (358.743 us; speedup 1.0000x reference)
//
#include <hip/hip_runtime.h>

// ISTFT = (Hermitian-folded windowed-IDFT GEMM) + overlap-add + wss normalize.
//
//   s[b,o,t] = sum_{j=0}^{1024} c_j*(W_real[o,j]*fr[b,j,t] - W_imag[o,j]*fi[b,j,t])
//   c_0 = c_1024 = 1, else 2   (from Hermitian symmetry of the full spectrum
//   and W_real/W_imag even/odd symmetry in j <-> 2048-j).
//
// GEMM: S[n=(b,t)][o] = sum_k X[n][k]*W[o][k], K padded 2050 -> 2112 (66*32),
// imag half at offset KH=1056. X carries the c_j scale and the minus sign on fi.
// Overlap-add: s[b,o,t] -> y[b, 512t+o]; each output sums <=4 frames; then /wss.

#define N_FFT   2048
#define HOP     512
#define T_FRAMES 1000
#define F_BINS  1025
#define NROWS   8000       // B*T
#define KH      1056
#define KP      2112
#define OUT_LEN 511488

typedef __attribute__((ext_vector_type(8))) short  short8;   // 8 bf16 = 4 VGPRs
typedef __attribute__((ext_vector_type(4))) float  float4v;  // MFMA acc

__device__ inline unsigned short f2bf(float f) {
    union { float f; unsigned int u; } v; v.f = f;
    unsigned int u = v.u;
    u += 0x7fffu + ((u >> 16) & 1u);    // round-to-nearest-even
    return (unsigned short)(u >> 16);
}

// X[n*KP + k] = bf16(c_k * fr[n,k])  (k<1025),  bf16(-c_j * fi[n,j]) (k=KH+j), else 0
__global__ __launch_bounds__(256) void prep_x_kernel(const float* __restrict__ re,
                                                     const float* __restrict__ im,
                                                     unsigned short* __restrict__ X) {
    int idx = blockIdx.x * 256 + threadIdx.x;       // exact: 8000*2112 = 66000*256
    int n = idx / KP, k = idx - n * KP;
    float val = 0.f;
    if (k < F_BINS) {
        float c = (k == 0 || k == F_BINS - 1) ? 1.f : 2.f;
        val = c * re[(size_t)n * F_BINS + k];
    } else if (k >= KH && k < KH + F_BINS) {
        int j = k - KH;
        float c = (j == 0 || j == F_BINS - 1) ? 1.f : 2.f;
        val = -c * im[(size_t)n * F_BINS + j];
    }
    X[idx] = f2bf(val);
}

// Wb[o*KP + k] = bf16(W_real[o,k]) (k<1025), bf16(W_imag[o,j]) (k=KH+j), else 0
__global__ __launch_bounds__(256) void prep_w_kernel(const float* __restrict__ Wr,
                                                     const float* __restrict__ Wi,
                                                     unsigned short* __restrict__ Wb) {
    int idx = blockIdx.x * 256 + threadIdx.x;       // exact: 2048*2112 = 16896*256
    int o = idx / KP, k = idx - o * KP;
    float val = 0.f;
    if (k < F_BINS)                        val = Wr[(size_t)o * N_FFT + k];
    else if (k >= KH && k < KH + F_BINS)   val = Wi[(size_t)o * N_FFT + (k - KH)];
    Wb[idx] = f2bf(val);
}

// 64x64 tile per 256-thread block (4 waves in 2x2, each wave a 32x32 of
// 16x16x32 MFMAs). Both operands are K-contiguous row-major ("B^T GEMM").
__global__ __launch_bounds__(256) void gemm_kernel(const unsigned short* __restrict__ X,
                                                   const unsigned short* __restrict__ W,
                                                   float* __restrict__ S) {
    __shared__ unsigned short As[64 * 40];   // [m][k], stride 40 bf16 = 80 B (16B aligned)
    __shared__ unsigned short Bs[64 * 40];   // [o][k]

    int tid  = threadIdx.x;
    int bm   = blockIdx.x;                   // 125 n-tiles
    int bn   = blockIdx.y;                   // 32 o-tiles
    int wave = tid >> 6, lane = tid & 63;
    int wm   = (wave & 1) * 32, wn = (wave >> 1) * 32;
    int l15  = lane & 15, q = lane >> 4;

    // staging: 64 rows x 32 k = 2048 bf16 per tile; 256 thr x 8 bf16 (16B) each
    int srow  = tid >> 2;
    int skcol = (tid & 3) * 8;
    const unsigned short* Xg = X + (size_t)(bm * 64 + srow) * KP + skcol;
    const unsigned short* Wg = W + (size_t)(bn * 64 + srow) * KP + skcol;
    unsigned short* Asw = As + srow * 40 + skcol;
    unsigned short* Bsw = Bs + srow * 40 + skcol;

    // fragment read ptrs: A[m=lane&15][k=quad*8+j]  (8 consecutive k -> b128)
    const short8* Ar0 = (const short8*)(As + (wm      + l15) * 40 + q * 8);
    const short8* Ar1 = (const short8*)(As + (wm + 16 + l15) * 40 + q * 8);
    const short8* Br0 = (const short8*)(Bs + (wn      + l15) * 40 + q * 8);
    const short8* Br1 = (const short8*)(Bs + (wn + 16 + l15) * 40 + q * 8);

    float4v acc00 = {0.f,0.f,0.f,0.f}, acc01 = {0.f,0.f,0.f,0.f};
    float4v acc10 = {0.f,0.f,0.f,0.f}, acc11 = {0.f,0.f,0.f,0.f};

    for (int k0 = 0; k0 < KP; k0 += 32) {
        short8 av = *(const short8*)Xg;      // issue global loads early
        short8 bv = *(const short8*)Wg;
        __syncthreads();                     // prev iter's LDS reads done
        *(short8*)Asw = av;
        *(short8*)Bsw = bv;
        __syncthreads();
        short8 a0 = *Ar0, a1 = *Ar1, b0 = *Br0, b1 = *Br1;
        acc00 = __builtin_amdgcn_mfma_f32_16x16x32_bf16(a0, b0, acc00, 0, 0, 0);
        acc01 = __builtin_amdgcn_mfma_f32_16x16x32_bf16(a0, b1, acc01, 0, 0, 0);
        acc10 = __builtin_amdgcn_mfma_f32_16x16x32_bf16(a1, b0, acc10, 0, 0, 0);
        acc11 = __builtin_amdgcn_mfma_f32_16x16x32_bf16(a1, b1, acc11, 0, 0, 0);
        Xg += 32; Wg += 32;
    }

    // C/D layout: col = lane&15, row = quad*4 + r   (verified m89/m91)
    int nbase = bm * 64 + wm;
    int obase = bn * 64 + wn;
    for (int r = 0; r < 4; ++r) {
        int nr0 = nbase + q * 4 + r;
        int nr1 = nr0 + 16;
        S[(size_t)nr0 * N_FFT + obase +      l15] = acc00[r];
        S[(size_t)nr0 * N_FFT + obase + 16 + l15] = acc01[r];
        S[(size_t)nr1 * N_FFT + obase +      l15] = acc10[r];
        S[(size_t)nr1 * N_FFT + obase + 16 + l15] = acc11[r];
    }
}

// out[b, m] = (sum_t S[b,t, n-512t]) / wss(n),  n = m + 1024
__global__ __launch_bounds__(256) void oa_kernel(const float* __restrict__ S,
                                                 const float* __restrict__ win,
                                                 float* __restrict__ out) {
    int m = blockIdx.x * 256 + threadIdx.x;  // exact: 511488 = 1998*256
    int b = blockIdx.y;
    int n = m + N_FFT / 2;
    int thi = n >> 9; if (thi > T_FRAMES - 1) thi = T_FRAMES - 1;
    int tlo = (n - (N_FFT - HOP)) >> 9; if (tlo < 0) tlo = 0;  // floor((n-2047)/512) clamped

    float sum = 0.f, wss = 0.f;
    for (int t = tlo; t <= thi; ++t) {
        int o = n - (t << 9);
        sum += S[((size_t)(b * T_FRAMES + t)) * N_FFT + o];
        float w = win[o];
        wss += w * w;
    }
    out[(size_t)b * OUT_LEN + m] = (wss > 1.17549435e-38f) ? sum / wss : sum;
}

extern "C" void kernel_launch(void* const* d_in, const int* in_sizes, int n_in,
                              void* d_out, int out_size, void* d_ws, size_t ws_size,
                              hipStream_t stream) {
    const float* re  = (const float*)d_in[0];
    const float* im  = (const float*)d_in[1];
    const float* Wr  = (const float*)d_in[2];
    const float* Wi  = (const float*)d_in[3];
    const float* win = (const float*)d_in[4];
    float* out = (float*)d_out;

    unsigned char* ws = (unsigned char*)d_ws;
    unsigned short* Xbf = (unsigned short*)ws;                         // 8000*2112*2  = 33,792,000 B
    unsigned short* Wbf = (unsigned short*)(ws + 33792000);            // 2048*2112*2  =  8,650,752 B
    float*          S   = (float*)(ws + 33792000 + 8650752);           // 8000*2048*4  = 65,536,000 B

    prep_x_kernel<<<66000, 256, 0, stream>>>(re, im, Xbf);
    prep_w_kernel<<<16896, 256, 0, stream>>>(Wr, Wi, Wbf);
    gemm_kernel<<<dim3(125, 32), 256, 0, stream>>>(Xbf, Wbf, S);
    oa_kernel<<<dim3(1998, 8), 256, 0, stream>>>(S, win, out);
}

// Round 2
// 270.359 us; speedup vs baseline: 1.3269x; 1.3269x over previous
//
#include <hip/hip_runtime.h>

// ISTFT = (Hermitian-folded windowed-IDFT GEMM) + overlap-add + wss normalize.
//
//   s[b,o,t] = sum_{j=0}^{1024} c_j*(W_real[o,j]*fr[b,j,t] - W_imag[o,j]*fi[b,j,t])
//   c_0 = c_1024 = 1, else 2.
//
// GEMM: S[n=(b,t)][o] = sum_k X[n][k]*W[o][k], K padded 2050 -> 2112 (33*64),
// imag half at offset KH=1056. X carries the c_j scale and the minus sign.
// m97-structure GEMM: 128x128 tile, BK=64, global_load_lds width=16,
// XOR-swizzled LDS (swizzle applied to the GLOBAL source k-block so the LDS
// destination stays lane-contiguous as global_load_lds requires).

#define N_FFT    2048
#define HOP      512
#define T_FRAMES 1000
#define F_BINS   1025
#define NROWS    8000      // B*T
#define KH       1056
#define KP       2112
#define OUT_LEN  511488

typedef __attribute__((ext_vector_type(8))) short  short8;   // 8 bf16 = 4 VGPRs
typedef __attribute__((ext_vector_type(4))) float  float4v;  // MFMA acc

typedef const __attribute__((address_space(1))) unsigned int g_u32;
typedef __attribute__((address_space(3))) unsigned int       l_u32;

__device__ __forceinline__ void gll16(const void* g, void* l) {
    // async global -> LDS, 16 B/lane; LDS dest = wave-uniform base + lane*16
    __builtin_amdgcn_global_load_lds((g_u32*)g, (l_u32*)l, 16, 0, 0);
}

__device__ __forceinline__ unsigned short f2bf(float f) {
    union { float f; unsigned int u; } v; v.f = f;
    unsigned int u = v.u;
    u += 0x7fffu + ((u >> 16) & 1u);    // round-to-nearest-even
    return (unsigned short)(u >> 16);
}

// X[n*KP + k] = bf16(c_k*fr[n,k]) (k<1025), bf16(-c_j*fi[n,j]) (k=KH+j), else 0
// 8 outputs per thread, one short8 (16 B) store. 2,112,000 threads = 8250*256.
__global__ __launch_bounds__(256) void prep_x_kernel(const float* __restrict__ re,
                                                     const float* __restrict__ im,
                                                     unsigned short* __restrict__ X) {
    int idx = blockIdx.x * 256 + threadIdx.x;
    int n  = idx / (KP / 8);
    int kb = idx - n * (KP / 8);
    int k0 = kb * 8;
    float v[8];
    if (k0 < KH) {
        const float* src = re + (size_t)n * F_BINS;
        #pragma unroll
        for (int j = 0; j < 8; ++j) {
            int k = k0 + j;
            float c = (k == 0 || k == F_BINS - 1) ? 1.f : 2.f;
            v[j] = (k < F_BINS) ? c * src[k] : 0.f;
        }
    } else {
        const float* src = im + (size_t)n * F_BINS;
        #pragma unroll
        for (int j = 0; j < 8; ++j) {
            int k = k0 - KH + j;
            float c = (k == 0 || k == F_BINS - 1) ? -1.f : -2.f;
            v[j] = (k < F_BINS) ? c * src[k] : 0.f;
        }
    }
    short8 o;
    #pragma unroll
    for (int j = 0; j < 8; ++j) o[j] = (short)f2bf(v[j]);
    *(short8*)(X + (size_t)idx * 8) = o;
}

// Wb[o*KP + k] = bf16(W_real[o,k]) (k<1025), bf16(W_imag[o,j]) (k=KH+j), else 0
// 540,672 threads = 2112*256.
__global__ __launch_bounds__(256) void prep_w_kernel(const float* __restrict__ Wr,
                                                     const float* __restrict__ Wi,
                                                     unsigned short* __restrict__ Wb) {
    int idx = blockIdx.x * 256 + threadIdx.x;
    int o  = idx / (KP / 8);
    int kb = idx - o * (KP / 8);
    int k0 = kb * 8;
    const float* src = (k0 < KH) ? (Wr + (size_t)o * N_FFT) : (Wi + (size_t)o * N_FFT);
    int base = (k0 < KH) ? k0 : (k0 - KH);
    short8 ov;
    #pragma unroll
    for (int j = 0; j < 8; ++j) {
        int k = base + j;
        float val = (k < F_BINS) ? src[k] : 0.f;
        ov[j] = (short)f2bf(val);
    }
    *(short8*)(Wb + (size_t)idx * 8) = ov;
}

// 128x128 tile, BK=64. 4 waves in 2x2; each wave 64x64 = 4x4 grid of 16x16.
// LDS layout (both A and B): logical (row, kblock kb [8 bf16 each]) stored at
// byte row*128 + (kb ^ (row&7))*16  -> fragment ds_read_b128 is 2-way (free),
// and staging writes are lane-contiguous (swizzle folded into global src).
__global__ __launch_bounds__(256, 4) void gemm_kernel(const unsigned short* __restrict__ X,
                                                      const unsigned short* __restrict__ W,
                                                      float* __restrict__ S) {
    __shared__ __attribute__((aligned(16))) unsigned short As[128 * 64];
    __shared__ __attribute__((aligned(16))) unsigned short Bs[128 * 64];

    const int tid = threadIdx.x;
    const int bm = blockIdx.x;          // 63 m-tiles (last partial, clamp rows)
    const int bn = blockIdx.y;          // 16 n-tiles

    // ---- staging addresses: 4 loads each for A and B, 16 B/lane ----
    const int srow = tid >> 3;                  // 0..31
    const int skb  = (tid & 7) ^ (srow & 7);    // swizzled global k-block
    const unsigned short* ga[4];
    const unsigned short* gb[4];
    #pragma unroll
    for (int i = 0; i < 4; ++i) {
        int ra = bm * 128 + i * 32 + srow; if (ra > NROWS - 1) ra = NROWS - 1;
        int rb = bn * 128 + i * 32 + srow;
        ga[i] = X + (size_t)ra * KP + skb * 8;
        gb[i] = W + (size_t)rb * KP + skb * 8;
    }
    unsigned short* lA = As + tid * 8;   // + i*2048 shorts (=4096 B) per load
    unsigned short* lB = Bs + tid * 8;

    // ---- fragment read bases (swz = (q+kk*4) ^ (l15&7), indep. of frag idx) ----
    const int wave = tid >> 6, lane = tid & 63;
    const int l15 = lane & 15, q = lane >> 4;
    const int wm = (wave & 1) * 64, wn = (wave >> 1) * 64;

    const unsigned short* pA[2];
    const unsigned short* pB[2];
    #pragma unroll
    for (int kk = 0; kk < 2; ++kk) {
        int swz = (q + kk * 4) ^ (l15 & 7);
        pA[kk] = As + (wm + l15) * 64 + swz * 8;   // + a*1024 shorts per frag
        pB[kk] = Bs + (wn + l15) * 64 + swz * 8;
    }

    float4v acc[4][4];
    #pragma unroll
    for (int a = 0; a < 4; ++a)
        #pragma unroll
        for (int b = 0; b < 4; ++b)
            acc[a][b] = (float4v){0.f, 0.f, 0.f, 0.f};

    for (int it = 0; it < KP / 64; ++it) {
        __syncthreads();                       // prev iter's LDS reads done
        #pragma unroll
        for (int i = 0; i < 4; ++i) {
            gll16(ga[i], lA + i * 2048);
            gll16(gb[i], lB + i * 2048);
        }
        __syncthreads();                       // vmcnt(0) drain + barrier
        #pragma unroll
        for (int kk = 0; kk < 2; ++kk) {
            short8 af[4], bf[4];
            #pragma unroll
            for (int a = 0; a < 4; ++a) af[a] = *(const short8*)(pA[kk] + a * 1024);
            #pragma unroll
            for (int b = 0; b < 4; ++b) bf[b] = *(const short8*)(pB[kk] + b * 1024);
            #pragma unroll
            for (int a = 0; a < 4; ++a)
                #pragma unroll
                for (int b = 0; b < 4; ++b)
                    acc[a][b] = __builtin_amdgcn_mfma_f32_16x16x32_bf16(af[a], bf[b], acc[a][b], 0, 0, 0);
        }
        #pragma unroll
        for (int i = 0; i < 4; ++i) { ga[i] += 64; gb[i] += 64; }
    }

    // C/D layout: col = lane&15, row = quad*4 + r  (verified m89/m91)
    const int obase = bn * 128 + wn + l15;
    #pragma unroll
    for (int a = 0; a < 4; ++a) {
        int nr_base = bm * 128 + wm + a * 16 + q * 4;
        #pragma unroll
        for (int r = 0; r < 4; ++r) {
            int nr = nr_base + r;
            if (nr < NROWS) {
                float* dst = S + (size_t)nr * N_FFT + obase;
                #pragma unroll
                for (int b = 0; b < 4; ++b) dst[b * 16] = acc[a][b][r];
            }
        }
    }
}

// out[b, m] = (sum_t S[b,t, n-512t]) / wss(n),  n = m + 1024
__global__ __launch_bounds__(256) void oa_kernel(const float* __restrict__ S,
                                                 const float* __restrict__ win,
                                                 float* __restrict__ out) {
    int m = blockIdx.x * 256 + threadIdx.x;  // exact: 511488 = 1998*256
    int b = blockIdx.y;
    int n = m + N_FFT / 2;
    int thi = n >> 9; if (thi > T_FRAMES - 1) thi = T_FRAMES - 1;
    int tlo = (n - (N_FFT - HOP)) >> 9; if (tlo < 0) tlo = 0;

    float sum = 0.f, wss = 0.f;
    for (int t = tlo; t <= thi; ++t) {
        int o = n - (t << 9);
        sum += S[((size_t)(b * T_FRAMES + t)) * N_FFT + o];
        float w = win[o];
        wss += w * w;
    }
    out[(size_t)b * OUT_LEN + m] = (wss > 1.17549435e-38f) ? sum / wss : sum;
}

extern "C" void kernel_launch(void* const* d_in, const int* in_sizes, int n_in,
                              void* d_out, int out_size, void* d_ws, size_t ws_size,
                              hipStream_t stream) {
    const float* re  = (const float*)d_in[0];
    const float* im  = (const float*)d_in[1];
    const float* Wr  = (const float*)d_in[2];
    const float* Wi  = (const float*)d_in[3];
    const float* win = (const float*)d_in[4];
    float* out = (float*)d_out;

    unsigned char* ws = (unsigned char*)d_ws;
    unsigned short* Xbf = (unsigned short*)ws;                 // 8000*2112*2 = 33,792,000 B
    unsigned short* Wbf = (unsigned short*)(ws + 33792000);    // 2048*2112*2 =  8,650,752 B
    float*          S   = (float*)(ws + 33792000 + 8650752);   // 8000*2048*4 = 65,536,000 B

    prep_x_kernel<<<8250, 256, 0, stream>>>(re, im, Xbf);
    prep_w_kernel<<<2112, 256, 0, stream>>>(Wr, Wi, Wbf);
    gemm_kernel<<<dim3(63, 16), 256, 0, stream>>>(Xbf, Wbf, S);
    oa_kernel<<<dim3(1998, 8), 256, 0, stream>>>(S, win, out);
}